// Round 1
// baseline (369.602 us; speedup 1.0000x reference)
//
#include <hip/hip_runtime.h>
#include <math.h>

#define B_  4
#define T_  2048
#define C_  1024
#define HD_ 64

// ---------------------------------------------------------------------------
// Kernel 1: QKV projection.  q/k/v[b,t,h] = sum_c x[b,t,c] * W{q,k,v}[c,h]
// Tiled fp32 GEMM: BM=32 rows, BN=64 cols (=HD), BK=32.
// grid (256 row-tiles, 3 matrices), block 256.  Thread tile 2 rows x 4 cols.
// ---------------------------------------------------------------------------
__global__ __launch_bounds__(256) void qkv_proj_kernel(
    const float* __restrict__ x,
    const float* __restrict__ Wq,
    const float* __restrict__ Wk,
    const float* __restrict__ Wv,
    float* __restrict__ qkv)
{
    __shared__ __align__(16) float as[32][36];   // x tile, pad 36 (9 float4)
    __shared__ __align__(16) float bs[32][68];   // W tile, pad 68 (17 float4)

    const int t  = threadIdx.x;
    const int rg = t & 15;        // row group: rows rg, rg+16
    const int cg = t >> 4;        // col group: cols 4cg..4cg+3
    const int mtx = blockIdx.y;
    const float* W = (mtx == 0) ? Wq : (mtx == 1) ? Wk : Wv;
    float* O = qkv + (size_t)mtx * ((size_t)B_ * T_ * HD_);
    const int R0 = blockIdx.x * 32;

    const int xr = t >> 3;            // 0..31
    const int xc = (t & 7) * 4;       // 0..28
    const int wr = t >> 4;            // 0..15
    const int wc = (t & 15) * 4;      // 0..60

    const float* xp  = x + (size_t)(R0 + xr) * C_ + xc;
    const float* wp0 = W + (size_t)wr * HD_ + wc;
    const float* wp1 = W + (size_t)(wr + 16) * HD_ + wc;

    float acc0[4] = {0.f, 0.f, 0.f, 0.f};
    float acc1[4] = {0.f, 0.f, 0.f, 0.f};

    // software-pipelined staging registers
    float4 xa = *(const float4*)xp;
    float4 wa = *(const float4*)wp0;
    float4 wb = *(const float4*)wp1;

    for (int c0 = 0; c0 < C_; c0 += 32) {
        __syncthreads();
        *(float4*)&as[xr][xc]      = xa;
        *(float4*)&bs[wr][wc]      = wa;
        *(float4*)&bs[wr + 16][wc] = wb;
        if (c0 + 32 < C_) {
            xa = *(const float4*)(xp + (c0 + 32));
            wa = *(const float4*)(wp0 + (size_t)(c0 + 32) * HD_);
            wb = *(const float4*)(wp1 + (size_t)(c0 + 32) * HD_);
        }
        __syncthreads();
        #pragma unroll
        for (int k = 0; k < 32; k += 4) {
            float4 a0 = *(const float4*)&as[rg][k];
            float4 a1 = *(const float4*)&as[rg + 16][k];
            float4 b0 = *(const float4*)&bs[k + 0][cg * 4];
            float4 b1 = *(const float4*)&bs[k + 1][cg * 4];
            float4 b2 = *(const float4*)&bs[k + 2][cg * 4];
            float4 b3 = *(const float4*)&bs[k + 3][cg * 4];
            acc0[0] += a0.x*b0.x + a0.y*b1.x + a0.z*b2.x + a0.w*b3.x;
            acc0[1] += a0.x*b0.y + a0.y*b1.y + a0.z*b2.y + a0.w*b3.y;
            acc0[2] += a0.x*b0.z + a0.y*b1.z + a0.z*b2.z + a0.w*b3.z;
            acc0[3] += a0.x*b0.w + a0.y*b1.w + a0.z*b2.w + a0.w*b3.w;
            acc1[0] += a1.x*b0.x + a1.y*b1.x + a1.z*b2.x + a1.w*b3.x;
            acc1[1] += a1.x*b0.y + a1.y*b1.y + a1.z*b2.y + a1.w*b3.y;
            acc1[2] += a1.x*b0.z + a1.y*b1.z + a1.z*b2.z + a1.w*b3.z;
            acc1[3] += a1.x*b0.w + a1.y*b1.w + a1.z*b2.w + a1.w*b3.w;
        }
    }
    *(float4*)&O[(size_t)(R0 + rg) * HD_ + cg * 4] =
        make_float4(acc0[0], acc0[1], acc0[2], acc0[3]);
    *(float4*)&O[(size_t)(R0 + rg + 16) * HD_ + cg * 4] =
        make_float4(acc1[0], acc1[1], acc1[2], acc1[3]);
}

// ---------------------------------------------------------------------------
// Kernel 2: double-softmax attention.
// Block = (batch b, pair p): handles 16-row tile A (rows 16p..16p+15) and
// 16-row tile B (rows 16(127-p)..): pairing makes causal work constant.
// Sweep 1: full-row online softmax stats (m,l).  Sweep 2: recompute scores
// for causal tiles, p = exp(s-m)/l, e = exp(p) (no max needed: p in [0,1]),
// accumulate out = sum e*v and den = sum e.
// Thread tile: 2 rows (rg, rg+16) x 4 cols (4cg..4cg+3); 256 threads.
// ---------------------------------------------------------------------------
__global__ __launch_bounds__(256) void attn_kernel(
    const float* __restrict__ q,
    const float* __restrict__ k,
    const float* __restrict__ v,
    float* __restrict__ out)
{
    __shared__ __align__(16) float qs[32][68];
    __shared__ __align__(16) float ks[64][68];
    __shared__ __align__(16) float vs[64][68];
    __shared__ __align__(16) float es[32][68];
    __shared__ float redm[32][4];
    __shared__ float redl[32][4];

    const int t  = threadIdx.x;
    const int rg = t & 15;
    const int cg = t >> 4;        // 0..15
    const int wv = t >> 6;        // wave 0..3

    const int b  = blockIdx.x >> 6;
    const int p  = blockIdx.x & 63;
    const int tB = 127 - p;
    const int IA = p * 16;
    const int IB = tB * 16;

    const float* qb = q + (size_t)b * T_ * HD_;
    const float* kb = k + (size_t)b * T_ * HD_;
    const float* vb = v + (size_t)b * T_ * HD_;
    float* ob = out + (size_t)b * T_ * HD_;

    // ---- load q tile (rows: 16 of A then 16 of B), pre-scaled by sqrt(HD)=8
    #pragma unroll
    for (int u = 0; u < 2; ++u) {
        int i  = t + u * 256;
        int r  = i >> 4;
        int d4 = (i & 15) * 4;
        int grow = (r < 16) ? (IA + r) : (IB + (r - 16));
        float4 val = *(const float4*)&qb[(size_t)grow * HD_ + d4];
        val.x *= 8.f; val.y *= 8.f; val.z *= 8.f; val.w *= 8.f;
        *(float4*)&qs[r][d4] = val;
    }

    float4 pk[4], pv4[4];
    auto loadK = [&](int jt) {
        const float4* src = (const float4*)(kb + (size_t)jt * 64 * HD_);
        #pragma unroll
        for (int u = 0; u < 4; ++u) pk[u] = src[t + u * 256];
    };
    auto storeK = [&]() {
        #pragma unroll
        for (int u = 0; u < 4; ++u) {
            int i = t + u * 256;
            *(float4*)&ks[i >> 4][(i & 15) * 4] = pk[u];
        }
    };
    auto loadV = [&](int jt) {
        const float4* src = (const float4*)(vb + (size_t)jt * 64 * HD_);
        #pragma unroll
        for (int u = 0; u < 4; ++u) pv4[u] = src[t + u * 256];
    };
    auto storeV = [&]() {
        #pragma unroll
        for (int u = 0; u < 4; ++u) {
            int i = t + u * 256;
            *(float4*)&vs[i >> 4][(i & 15) * 4] = pv4[u];
        }
    };

    // ================= sweep 1: full-row softmax stats =================
    float m0 = -INFINITY, m1 = -INFINITY, l0 = 0.f, l1 = 0.f;
    loadK(0);
    for (int jt = 0; jt < 32; ++jt) {
        __syncthreads();
        storeK();
        if (jt + 1 < 32) loadK(jt + 1);
        __syncthreads();
        float s0[4] = {0.f, 0.f, 0.f, 0.f};
        float s1[4] = {0.f, 0.f, 0.f, 0.f};
        #pragma unroll
        for (int d = 0; d < HD_; d += 4) {
            float4 qa = *(const float4*)&qs[rg][d];
            float4 qc = *(const float4*)&qs[rg + 16][d];
            #pragma unroll
            for (int j = 0; j < 4; ++j) {
                float4 kk = *(const float4*)&ks[cg * 4 + j][d];
                s0[j] += qa.x*kk.x + qa.y*kk.y + qa.z*kk.z + qa.w*kk.w;
                s1[j] += qc.x*kk.x + qc.y*kk.y + qc.z*kk.z + qc.w*kk.w;
            }
        }
        float mt = fmaxf(fmaxf(s0[0], s0[1]), fmaxf(s0[2], s0[3]));
        float mn = fmaxf(m0, mt);
        l0 = l0 * __expf(m0 - mn)
           + __expf(s0[0] - mn) + __expf(s0[1] - mn)
           + __expf(s0[2] - mn) + __expf(s0[3] - mn);
        m0 = mn;
        mt = fmaxf(fmaxf(s1[0], s1[1]), fmaxf(s1[2], s1[3]));
        mn = fmaxf(m1, mt);
        l1 = l1 * __expf(m1 - mn)
           + __expf(s1[0] - mn) + __expf(s1[1] - mn)
           + __expf(s1[2] - mn) + __expf(s1[3] - mn);
        m1 = mn;
    }
    // merge across the 4 col-groups within each wave (lanes ^16, ^32)
    #pragma unroll
    for (int off = 16; off < 64; off <<= 1) {
        float mo = __shfl_xor(m0, off);
        float lo = __shfl_xor(l0, off);
        float mn2 = fmaxf(m0, mo);
        l0 = l0 * __expf(m0 - mn2) + lo * __expf(mo - mn2);
        m0 = mn2;
        mo = __shfl_xor(m1, off);
        lo = __shfl_xor(l1, off);
        mn2 = fmaxf(m1, mo);
        l1 = l1 * __expf(m1 - mn2) + lo * __expf(mo - mn2);
        m1 = mn2;
    }
    // merge across the 4 waves via LDS
    if ((t & 63) < 16) {
        redm[rg][wv] = m0;      redl[rg][wv] = l0;
        redm[rg + 16][wv] = m1; redl[rg + 16][wv] = l1;
    }
    __syncthreads();
    m0 = redm[rg][0]; l0 = redl[rg][0];
    #pragma unroll
    for (int w2 = 1; w2 < 4; ++w2) {
        float mo = redm[rg][w2], lo = redl[rg][w2];
        float mn2 = fmaxf(m0, mo);
        l0 = l0 * __expf(m0 - mn2) + lo * __expf(mo - mn2);
        m0 = mn2;
    }
    m1 = redm[rg + 16][0]; l1 = redl[rg + 16][0];
    #pragma unroll
    for (int w2 = 1; w2 < 4; ++w2) {
        float mo = redm[rg + 16][w2], lo = redl[rg + 16][w2];
        float mn2 = fmaxf(m1, mo);
        l1 = l1 * __expf(m1 - mn2) + lo * __expf(mo - mn2);
        m1 = mn2;
    }
    const float invl0 = 1.f / l0;
    const float invl1 = 1.f / l1;

    // ================= sweep 2: causal tiles, second softmax ============
    const int nA = p / 4 + 1;       // causal k-tiles for the A rows
    const int nB = tB / 4 + 1;      // causal k-tiles for the B rows (>= nA)
    const int ra = IA + rg;
    const int rb = IB + rg;
    float o0[4] = {0.f, 0.f, 0.f, 0.f};
    float o1[4] = {0.f, 0.f, 0.f, 0.f};
    float den0 = 0.f, den1 = 0.f;

    loadK(0); loadV(0);
    for (int jt = 0; jt < nB; ++jt) {
        __syncthreads();            // prev tile's ks/vs/es readers done
        storeK(); storeV();
        if (jt + 1 < nB) { loadK(jt + 1); loadV(jt + 1); }
        __syncthreads();
        const bool doA = (jt < nA);     // block-uniform branch
        float s0[4] = {0.f, 0.f, 0.f, 0.f};
        float s1[4] = {0.f, 0.f, 0.f, 0.f};
        if (doA) {
            #pragma unroll
            for (int d = 0; d < HD_; d += 4) {
                float4 qa = *(const float4*)&qs[rg][d];
                float4 qc = *(const float4*)&qs[rg + 16][d];
                #pragma unroll
                for (int j = 0; j < 4; ++j) {
                    float4 kk = *(const float4*)&ks[cg * 4 + j][d];
                    s0[j] += qa.x*kk.x + qa.y*kk.y + qa.z*kk.z + qa.w*kk.w;
                    s1[j] += qc.x*kk.x + qc.y*kk.y + qc.z*kk.z + qc.w*kk.w;
                }
            }
        } else {
            #pragma unroll
            for (int d = 0; d < HD_; d += 4) {
                float4 qc = *(const float4*)&qs[rg + 16][d];
                #pragma unroll
                for (int j = 0; j < 4; ++j) {
                    float4 kk = *(const float4*)&ks[cg * 4 + j][d];
                    s1[j] += qc.x*kk.x + qc.y*kk.y + qc.z*kk.z + qc.w*kk.w;
                }
            }
        }
        const int cb = jt * 64 + cg * 4;    // global col of this thread's cols
        {
            float e1v[4];
            #pragma unroll
            for (int j = 0; j < 4; ++j) {
                float p1 = __expf(s1[j] - m1) * invl1;
                e1v[j] = (cb + j <= rb) ? __expf(p1) : 0.f;
            }
            *(float4*)&es[rg + 16][cg * 4] =
                make_float4(e1v[0], e1v[1], e1v[2], e1v[3]);
            den1 += e1v[0] + e1v[1] + e1v[2] + e1v[3];
        }
        if (doA) {
            float e0v[4];
            #pragma unroll
            for (int j = 0; j < 4; ++j) {
                float p0 = __expf(s0[j] - m0) * invl0;
                e0v[j] = (cb + j <= ra) ? __expf(p0) : 0.f;
            }
            *(float4*)&es[rg][cg * 4] =
                make_float4(e0v[0], e0v[1], e0v[2], e0v[3]);
            den0 += e0v[0] + e0v[1] + e0v[2] + e0v[3];
        }
        __syncthreads();            // es visible to all
        if (doA) {
            #pragma unroll
            for (int jl = 0; jl < 64; jl += 4) {
                float4 e0 = *(const float4*)&es[rg][jl];
                float4 e1 = *(const float4*)&es[rg + 16][jl];
                float4 v0 = *(const float4*)&vs[jl + 0][cg * 4];
                float4 v1 = *(const float4*)&vs[jl + 1][cg * 4];
                float4 v2 = *(const float4*)&vs[jl + 2][cg * 4];
                float4 v3 = *(const float4*)&vs[jl + 3][cg * 4];
                o0[0] += e0.x*v0.x + e0.y*v1.x + e0.z*v2.x + e0.w*v3.x;
                o0[1] += e0.x*v0.y + e0.y*v1.y + e0.z*v2.y + e0.w*v3.y;
                o0[2] += e0.x*v0.z + e0.y*v1.z + e0.z*v2.z + e0.w*v3.z;
                o0[3] += e0.x*v0.w + e0.y*v1.w + e0.z*v2.w + e0.w*v3.w;
                o1[0] += e1.x*v0.x + e1.y*v1.x + e1.z*v2.x + e1.w*v3.x;
                o1[1] += e1.x*v0.y + e1.y*v1.y + e1.z*v2.y + e1.w*v3.y;
                o1[2] += e1.x*v0.z + e1.y*v1.z + e1.z*v2.z + e1.w*v3.z;
                o1[3] += e1.x*v0.w + e1.y*v1.w + e1.z*v2.w + e1.w*v3.w;
            }
        } else {
            #pragma unroll
            for (int jl = 0; jl < 64; jl += 4) {
                float4 e1 = *(const float4*)&es[rg + 16][jl];
                float4 v0 = *(const float4*)&vs[jl + 0][cg * 4];
                float4 v1 = *(const float4*)&vs[jl + 1][cg * 4];
                float4 v2 = *(const float4*)&vs[jl + 2][cg * 4];
                float4 v3 = *(const float4*)&vs[jl + 3][cg * 4];
                o1[0] += e1.x*v0.x + e1.y*v1.x + e1.z*v2.x + e1.w*v3.x;
                o1[1] += e1.x*v0.y + e1.y*v1.y + e1.z*v2.y + e1.w*v3.y;
                o1[2] += e1.x*v0.z + e1.y*v1.z + e1.z*v2.z + e1.w*v3.z;
                o1[3] += e1.x*v0.w + e1.y*v1.w + e1.z*v2.w + e1.w*v3.w;
            }
        }
    }

    // ---- denominator reduction + output
    den0 += __shfl_xor(den0, 16); den0 += __shfl_xor(den0, 32);
    den1 += __shfl_xor(den1, 16); den1 += __shfl_xor(den1, 32);
    __syncthreads();                // PV readers of es/vs done (reuse red*)
    if ((t & 63) < 16) {
        redm[rg][wv] = den0;
        redl[rg][wv] = den1;
    }
    __syncthreads();
    const float D0 = redm[rg][0] + redm[rg][1] + redm[rg][2] + redm[rg][3];
    const float D1 = redl[rg][0] + redl[rg][1] + redl[rg][2] + redl[rg][3];
    const float id0 = 1.f / D0;
    const float id1 = 1.f / D1;
    *(float4*)&ob[(size_t)ra * HD_ + cg * 4] =
        make_float4(o0[0]*id0, o0[1]*id0, o0[2]*id0, o0[3]*id0);
    *(float4*)&ob[(size_t)rb * HD_ + cg * 4] =
        make_float4(o1[0]*id1, o1[1]*id1, o1[2]*id1, o1[3]*id1);
}

// ---------------------------------------------------------------------------
extern "C" void kernel_launch(void* const* d_in, const int* in_sizes, int n_in,
                              void* d_out, int out_size, void* d_ws, size_t ws_size,
                              hipStream_t stream) {
    (void)in_sizes; (void)n_in; (void)out_size; (void)ws_size;
    const float* x  = (const float*)d_in[0];
    const float* Wq = (const float*)d_in[1];
    const float* Wk = (const float*)d_in[2];
    const float* Wv = (const float*)d_in[3];
    float* outp = (float*)d_out;
    float* qkv  = (float*)d_ws;                 // 3 * B*T*HD floats = 6 MB
    const size_t plane = (size_t)B_ * T_ * HD_;

    dim3 g1((B_ * T_) / 32, 3), b1(256);
    qkv_proj_kernel<<<g1, b1, 0, stream>>>(x, Wq, Wk, Wv, qkv);

    dim3 g2(B_ * (T_ / 16) / 2), b2(256);       // 4 * 64 = 256 blocks
    attn_kernel<<<g2, b2, 0, stream>>>(qkv, qkv + plane, qkv + 2 * plane, outp);
}

// Round 2
// 157.343 us; speedup vs baseline: 2.3490x; 2.3490x over previous
//
#include <hip/hip_runtime.h>
#include <math.h>

#define T_  2048
#define C_  1024
#define HD_ 64
#define BB_ 4

typedef __attribute__((ext_vector_type(8))) short bf16x8;   // 8 bf16 = 4 VGPRs
typedef __attribute__((ext_vector_type(4))) float f32x4;    // MFMA C/D

#define MFMA_BF16(A, B, C) __builtin_amdgcn_mfma_f32_16x16x32_bf16(A, B, C, 0, 0, 0)

__device__ __forceinline__ short f2bf(float f) {
    union { float f; unsigned u; } v; v.f = f;
    unsigned r = v.u + 0x7fffu + ((v.u >> 16) & 1u);   // RTNE
    return (short)(r >> 16);
}
__device__ __forceinline__ float bf2f(short s) {
    union { float f; unsigned u; } v;
    v.u = ((unsigned)(unsigned short)s) << 16;
    return v.f;
}

// ---------------------------------------------------------------------------
// K0: W[1024][64] fp32  ->  Wt[m][hi/lo][64 h][1024 c] bf16 (transposed+split)
// ---------------------------------------------------------------------------
__global__ __launch_bounds__(256) void prep_w_kernel(
    const float* __restrict__ Wq, const float* __restrict__ Wk,
    const float* __restrict__ Wv, short* __restrict__ wt)
{
    const int m = blockIdx.y;
    const float* W = (m == 0) ? Wq : (m == 1) ? Wk : Wv;
    const int t = threadIdx.x;
    const int c = blockIdx.x * 64 + (t >> 2);
    const int hg = (t & 3) * 16;
    const float4* wp = (const float4*)(W + (size_t)c * HD_ + hg);
    short* hi = wt + (size_t)(m * 2 + 0) * 64 * 1024;
    short* lo = wt + (size_t)(m * 2 + 1) * 64 * 1024;
    #pragma unroll
    for (int u = 0; u < 4; ++u) {
        float4 f = wp[u];
        float vv0 = f.x, vv1 = f.y, vv2 = f.z, vv3 = f.w;
        float vs[4] = {vv0, vv1, vv2, vv3};
        #pragma unroll
        for (int e = 0; e < 4; ++e) {
            int h = hg + u * 4 + e;
            short hh = f2bf(vs[e]);
            short ll = f2bf(vs[e] - bf2f(hh));
            hi[(size_t)h * 1024 + c] = hh;
            lo[(size_t)h * 1024 + c] = ll;
        }
    }
}

// ---------------------------------------------------------------------------
// K1: MFMA projection. Block = (64 rows of x, matrix m). 256 thr = 4 waves.
// q (x8 scale) and k stored as hi/lo bf16 planes [8192][64].
// v stored TRANSPOSED single bf16: vT[b][d][t]  (A/B operands swapped).
// LDS fragment arrays: [row][8 chunks of 8 bf16], slot = chunk ^ (row&7).
// ---------------------------------------------------------------------------
__global__ __launch_bounds__(256) void qkv_proj_kernel(
    const float* __restrict__ x, const short* __restrict__ wt,
    short* __restrict__ qhp, short* __restrict__ qlp,
    short* __restrict__ khp, short* __restrict__ klp,
    short* __restrict__ vtp)
{
    __shared__ __align__(16) short xh[64 * 64], xl[64 * 64];
    __shared__ __align__(16) short wh[64 * 64], wl[64 * 64];

    const int t  = threadIdx.x;
    const int L  = t & 63;
    const int wv = t >> 6;
    const int m  = blockIdx.y;
    const int R0 = blockIdx.x * 64;

    const int xt0 = (wv & 1) * 2;      // x-side tile pair (t-dim)
    const int wt0 = (wv >> 1) * 2;     // w-side tile pair (h-dim)

    f32x4 acc[2][2];
    #pragma unroll
    for (int i = 0; i < 2; ++i)
        #pragma unroll
        for (int j = 0; j < 2; ++j)
            acc[i][j] = {0.f, 0.f, 0.f, 0.f};

    const int sr  = t & 63;     // staging row
    const int scg = t >> 6;     // staging chunk group

    for (int c0 = 0; c0 < C_; c0 += 64) {
        __syncthreads();
        // ---- stage x (fp32 -> hi/lo bf16)
        {
            const float4* xp = (const float4*)(x + (size_t)(R0 + sr) * C_ + c0 + scg * 16);
            #pragma unroll
            for (int g = 0; g < 2; ++g) {
                bf16x8 vh, vl;
                #pragma unroll
                for (int u = 0; u < 2; ++u) {
                    float4 f = xp[g * 2 + u];
                    float vs[4] = {f.x, f.y, f.z, f.w};
                    #pragma unroll
                    for (int e = 0; e < 4; ++e) {
                        short hh = f2bf(vs[e]);
                        vh[u * 4 + e] = hh;
                        vl[u * 4 + e] = f2bf(vs[e] - bf2f(hh));
                    }
                }
                int ch = scg * 2 + g;
                int off = sr * 64 + ((ch ^ (sr & 7)) * 8);
                *(bf16x8*)&xh[off] = vh;
                *(bf16x8*)&xl[off] = vl;
            }
        }
        // ---- stage Wt (already bf16 hi/lo in global)
        {
            const int pl = t >> 7;        // 0 hi, 1 lo
            const int id = t & 127;
            const short* wsrc = wt + (size_t)(m * 2 + pl) * 64 * 1024;
            short* wdst = pl ? wl : wh;
            #pragma unroll
            for (int u = 0; u < 4; ++u) {
                int cid = id * 4 + u;             // 0..511
                int h = cid >> 3, c8 = cid & 7;
                bf16x8 v = *(const bf16x8*)(wsrc + (size_t)h * 1024 + c0 + c8 * 8);
                *(bf16x8*)&wdst[h * 64 + ((c8 ^ (h & 7)) * 8)] = v;
            }
        }
        __syncthreads();
        // ---- MFMA over 2 k-chunks of 32
        #pragma unroll
        for (int kc = 0; kc < 2; ++kc) {
            bf16x8 ax[2], axl[2], bw[2], bwl[2];
            #pragma unroll
            for (int i = 0; i < 2; ++i) {
                int row = (xt0 + i) * 16 + (L & 15);
                int ch  = kc * 4 + (L >> 4);
                int off = row * 64 + ((ch ^ (row & 7)) * 8);
                ax[i]  = *(const bf16x8*)&xh[off];
                axl[i] = *(const bf16x8*)&xl[off];
                int hrow = (wt0 + i) * 16 + (L & 15);
                int off2 = hrow * 64 + ((ch ^ (hrow & 7)) * 8);
                bw[i]  = *(const bf16x8*)&wh[off2];
                bwl[i] = *(const bf16x8*)&wl[off2];
            }
            if (m < 2) {
                #pragma unroll
                for (int i = 0; i < 2; ++i)
                    #pragma unroll
                    for (int j = 0; j < 2; ++j) {
                        acc[i][j] = MFMA_BF16(axl[i], bw[j], acc[i][j]);
                        acc[i][j] = MFMA_BF16(ax[i], bwl[j], acc[i][j]);
                        acc[i][j] = MFMA_BF16(ax[i], bw[j], acc[i][j]);
                    }
            } else {   // V: swap operands -> D[h][t] (transposed output)
                #pragma unroll
                for (int i = 0; i < 2; ++i)
                    #pragma unroll
                    for (int j = 0; j < 2; ++j) {
                        acc[i][j] = MFMA_BF16(bwl[j], ax[i], acc[i][j]);
                        acc[i][j] = MFMA_BF16(bw[j], axl[i], acc[i][j]);
                        acc[i][j] = MFMA_BF16(bw[j], ax[i], acc[i][j]);
                    }
            }
        }
    }

    // ---- epilogue
    if (m < 2) {
        short* ph = (m == 0) ? qhp : khp;
        short* pl = (m == 0) ? qlp : klp;
        const float sc = (m == 0) ? 8.f : 1.f;     // fold sqrt(HD)=8 into q
        #pragma unroll
        for (int i = 0; i < 2; ++i)
            #pragma unroll
            for (int j = 0; j < 2; ++j)
                #pragma unroll
                for (int r = 0; r < 4; ++r) {
                    int row = R0 + (xt0 + i) * 16 + (L >> 4) * 4 + r;
                    int h   = (wt0 + j) * 16 + (L & 15);
                    float v = acc[i][j][r] * sc;
                    short hh = f2bf(v);
                    ph[(size_t)row * HD_ + h] = hh;
                    pl[(size_t)row * HD_ + h] = f2bf(v - bf2f(hh));
                }
    } else {
        #pragma unroll
        for (int i = 0; i < 2; ++i)
            #pragma unroll
            for (int j = 0; j < 2; ++j)
                #pragma unroll
                for (int r = 0; r < 4; ++r) {
                    int d  = (wt0 + j) * 16 + (L >> 4) * 4 + r;
                    int tt = R0 + (xt0 + i) * 16 + (L & 15);
                    int bb = tt >> 11, tl = tt & (T_ - 1);
                    vtp[(size_t)(bb * 64 + d) * T_ + tl] = f2bf(acc[i][j][r]);
                }
    }
}

// ---------------------------------------------------------------------------
// K2: double-softmax attention, MFMA. Block = (batch, paired tiles p & 127-p),
// 512 thr = 8 waves. Sweep1: full-row (m,l). Sweep2: causal e=exp(p), PV MFMA.
// ---------------------------------------------------------------------------
__global__ __launch_bounds__(512) void attn_kernel(
    const short* __restrict__ qhp, const short* __restrict__ qlp,
    const short* __restrict__ khp, const short* __restrict__ klp,
    const short* __restrict__ vtp, float* __restrict__ out)
{
    __shared__ __align__(16) short khs[128 * 64];   // [col][d] 8 chunks, ^(col&7)
    __shared__ __align__(16) short kls[128 * 64];
    __shared__ __align__(16) short vts[64 * 128];   // [d][col] 16 chunks, ^((d&7)*2)
    __shared__ __align__(16) short ebs[32 * 128];   // [rid][col] 16 chunks, ^((rid&7)*2)
    __shared__ float red[8 * 32 * 2];
    __shared__ float mrow[32], ilrow[32], dinv[32];

    const int t  = threadIdx.x;
    const int L  = t & 63;
    const int wv = t >> 6;
    const int b  = blockIdx.x >> 6;
    const int p  = blockIdx.x & 63;
    const int IA = p * 16, IB = (127 - p) * 16;

    // ---- q fragments, resident for the whole kernel
    bf16x8 qfh[2][2], qfl[2][2];
    #pragma unroll
    for (int rt = 0; rt < 2; ++rt) {
        int row = (rt ? IB : IA) + (L & 15);
        const short* qb  = qhp + ((size_t)b * T_ + row) * HD_;
        const short* qbl = qlp + ((size_t)b * T_ + row) * HD_;
        #pragma unroll
        for (int dc = 0; dc < 2; ++dc) {
            int off = dc * 32 + (L >> 4) * 8;
            qfh[rt][dc] = *(const bf16x8*)(qb + off);
            qfl[rt][dc] = *(const bf16x8*)(qbl + off);
        }
    }

    const short* kbh = khp + (size_t)b * T_ * HD_;
    const short* kbl = klp + (size_t)b * T_ * HD_;
    const short* vb  = vtp + (size_t)b * 64 * T_;

    const int spl = t >> 8;        // K staging plane: 0 hi (waves 0-3), 1 lo
    const int sid = t & 255;

    auto stageK = [&](int jt) {
        const short* src = spl ? kbl : kbh;
        short* dst = spl ? kls : khs;
        #pragma unroll
        for (int u = 0; u < 4; ++u) {
            int cid = sid * 4 + u;                 // 0..1023
            int col = cid >> 3, c8 = cid & 7;
            bf16x8 v = *(const bf16x8*)(src + (size_t)(jt * 128 + col) * HD_ + c8 * 8);
            *(bf16x8*)&dst[col * 64 + ((c8 ^ (col & 7)) * 8)] = v;
        }
    };
    auto stageV = [&](int jt) {
        #pragma unroll
        for (int u = 0; u < 2; ++u) {
            int cid = t + u * 512;                 // 0..1023
            int d = cid >> 4, ch = cid & 15;
            bf16x8 v = *(const bf16x8*)(vb + (size_t)d * T_ + jt * 128 + ch * 8);
            *(bf16x8*)&vts[d * 128 + ((ch ^ ((d & 7) * 2)) * 8)] = v;
        }
    };

    // ================= sweep 1: full-row softmax stats =================
    float ml[2][4], ll[2][4];
    #pragma unroll
    for (int rt = 0; rt < 2; ++rt)
        #pragma unroll
        for (int r = 0; r < 4; ++r) { ml[rt][r] = -1e30f; ll[rt][r] = 0.f; }

    for (int jt = 0; jt < 16; ++jt) {
        __syncthreads();
        stageK(jt);
        __syncthreads();
        const int col = wv * 16 + (L & 15);
        bf16x8 kf[2], kfl[2];
        #pragma unroll
        for (int dc = 0; dc < 2; ++dc) {
            int ch = dc * 4 + (L >> 4);
            int off = col * 64 + ((ch ^ (col & 7)) * 8);
            kf[dc]  = *(const bf16x8*)&khs[off];
            kfl[dc] = *(const bf16x8*)&kls[off];
        }
        #pragma unroll
        for (int rt = 0; rt < 2; ++rt) {
            f32x4 s = {0.f, 0.f, 0.f, 0.f};
            #pragma unroll
            for (int dc = 0; dc < 2; ++dc) {
                s = MFMA_BF16(qfl[rt][dc], kf[dc], s);
                s = MFMA_BF16(qfh[rt][dc], kfl[dc], s);
                s = MFMA_BF16(qfh[rt][dc], kf[dc], s);
            }
            #pragma unroll
            for (int r = 0; r < 4; ++r) {
                float sv = s[r];
                float mn = fmaxf(ml[rt][r], sv);
                ll[rt][r] = ll[rt][r] * __expf(ml[rt][r] - mn) + __expf(sv - mn);
                ml[rt][r] = mn;
            }
        }
    }
    // merge 16 cols within wave
    #pragma unroll
    for (int off = 1; off < 16; off <<= 1)
        #pragma unroll
        for (int rt = 0; rt < 2; ++rt)
            #pragma unroll
            for (int r = 0; r < 4; ++r) {
                float mo = __shfl_xor(ml[rt][r], off, 64);
                float lo = __shfl_xor(ll[rt][r], off, 64);
                float mn = fmaxf(ml[rt][r], mo);
                ll[rt][r] = ll[rt][r] * __expf(ml[rt][r] - mn) + lo * __expf(mo - mn);
                ml[rt][r] = mn;
            }
    if ((L & 15) == 0) {
        #pragma unroll
        for (int rt = 0; rt < 2; ++rt)
            #pragma unroll
            for (int r = 0; r < 4; ++r) {
                int rid = rt * 16 + (L >> 4) * 4 + r;
                red[(wv * 32 + rid) * 2 + 0] = ml[rt][r];
                red[(wv * 32 + rid) * 2 + 1] = ll[rt][r];
            }
    }
    __syncthreads();
    if (t < 32) {
        float M = red[t * 2], S = red[t * 2 + 1];
        #pragma unroll
        for (int w = 1; w < 8; ++w) {
            float mo = red[(w * 32 + t) * 2], lo = red[(w * 32 + t) * 2 + 1];
            float mn = fmaxf(M, mo);
            S = S * __expf(M - mn) + lo * __expf(mo - mn);
            M = mn;
        }
        mrow[t] = M;
        ilrow[t] = 1.f / S;
    }
    __syncthreads();

    float ms[2][4], is[2][4];
    int rowg[2][4];
    #pragma unroll
    for (int rt = 0; rt < 2; ++rt)
        #pragma unroll
        for (int r = 0; r < 4; ++r) {
            int rid = rt * 16 + (L >> 4) * 4 + r;
            ms[rt][r] = mrow[rid];
            is[rt][r] = ilrow[rid];
            rowg[rt][r] = (rt ? IB : IA) + (L >> 4) * 4 + r;
        }

    // ================= sweep 2: causal, second softmax, PV ==============
    const int nA = (IA + 143) >> 7;
    const int nB = (IB + 143) >> 7;
    const int rtp = wv & 1, dh = (wv >> 1) & 1, khf = wv >> 2;
    f32x4 ov[2];
    ov[0] = {0.f, 0.f, 0.f, 0.f};
    ov[1] = {0.f, 0.f, 0.f, 0.f};
    float dn[2][4];
    #pragma unroll
    for (int rt = 0; rt < 2; ++rt)
        #pragma unroll
        for (int r = 0; r < 4; ++r) dn[rt][r] = 0.f;

    for (int jt = 0; jt < nB; ++jt) {
        __syncthreads();
        stageK(jt);
        stageV(jt);
        __syncthreads();
        // scores + e (each wave: 16-col strip, both row tiles)
        const int col = wv * 16 + (L & 15);
        bf16x8 kf[2], kfl[2];
        #pragma unroll
        for (int dc = 0; dc < 2; ++dc) {
            int ch = dc * 4 + (L >> 4);
            int off = col * 64 + ((ch ^ (col & 7)) * 8);
            kf[dc]  = *(const bf16x8*)&khs[off];
            kfl[dc] = *(const bf16x8*)&kls[off];
        }
        for (int rt = 0; rt < 2; ++rt) {
            if (rt == 0 && jt >= nA) continue;     // block-uniform
            f32x4 s = {0.f, 0.f, 0.f, 0.f};
            #pragma unroll
            for (int dc = 0; dc < 2; ++dc) {
                s = MFMA_BF16(qfl[rt][dc], kf[dc], s);
                s = MFMA_BF16(qfh[rt][dc], kfl[dc], s);
                s = MFMA_BF16(qfh[rt][dc], kf[dc], s);
            }
            #pragma unroll
            for (int r = 0; r < 4; ++r) {
                float pv = __expf(s[r] - ms[rt][r]) * is[rt][r];
                int colg = jt * 128 + col;
                float ev = (colg <= rowg[rt][r]) ? __expf(pv) : 0.f;
                short e16 = f2bf(ev);
                dn[rt][r] += bf2f(e16);            // den consistent with bf16 e
                int rid = rt * 16 + (L >> 4) * 4 + r;
                ebs[rid * 128 + (((col >> 3) ^ ((rid & 7) * 2)) * 8) + (col & 7)] = e16;
            }
        }
        __syncthreads();
        // PV: wave = (row tile rtp, d-half dh, k-half khf)
        if (!(rtp == 0 && jt >= nA)) {
            #pragma unroll
            for (int u = 0; u < 2; ++u) {
                int kc = khf * 2 + u;
                int rid = rtp * 16 + (L & 15);
                int ch = kc * 4 + (L >> 4);
                bf16x8 ef = *(const bf16x8*)&ebs[rid * 128 + ((ch ^ ((rid & 7) * 2)) * 8)];
                #pragma unroll
                for (int dt = 0; dt < 2; ++dt) {
                    int d = dh * 32 + dt * 16 + (L & 15);
                    bf16x8 vf = *(const bf16x8*)&vts[d * 128 + ((ch ^ ((d & 7) * 2)) * 8)];
                    ov[dt] = MFMA_BF16(ef, vf, ov[dt]);
                }
            }
        }
    }

    // ---- den reduce
    #pragma unroll
    for (int off = 1; off < 16; off <<= 1)
        #pragma unroll
        for (int rt = 0; rt < 2; ++rt)
            #pragma unroll
            for (int r = 0; r < 4; ++r)
                dn[rt][r] += __shfl_xor(dn[rt][r], off, 64);
    __syncthreads();                // all PV reads of ebs/vts done
    if ((L & 15) == 0) {
        #pragma unroll
        for (int rt = 0; rt < 2; ++rt)
            #pragma unroll
            for (int r = 0; r < 4; ++r) {
                int rid = rt * 16 + (L >> 4) * 4 + r;
                red[wv * 32 + rid] = dn[rt][r];
            }
    }
    __syncthreads();
    if (t < 32) {
        float D = 0.f;
        #pragma unroll
        for (int w = 0; w < 8; ++w) D += red[w * 32 + t];
        dinv[t] = 1.f / D;
    }
    // ---- O cross-k-half reduction (reuse ebs as fp32 buffer)
    float* obuf = (float*)ebs;      // 2048 floats = 8 KB
    __syncthreads();
    if (khf == 1) {
        #pragma unroll
        for (int dt = 0; dt < 2; ++dt)
            #pragma unroll
            for (int r = 0; r < 4; ++r)
                obuf[((wv - 4) * 64 + L) * 8 + dt * 4 + r] = ov[dt][r];
    }
    __syncthreads();
    if (khf == 0) {
        float* ob = out + (size_t)b * T_ * HD_;
        #pragma unroll
        for (int dt = 0; dt < 2; ++dt)
            #pragma unroll
            for (int r = 0; r < 4; ++r) {
                float o = ov[dt][r] + obuf[(wv * 64 + L) * 8 + dt * 4 + r];
                int rid = rtp * 16 + (L >> 4) * 4 + r;
                int row = (rtp ? IB : IA) + (L >> 4) * 4 + r;
                int d = dh * 32 + dt * 16 + (L & 15);
                ob[(size_t)row * HD_ + d] = o * dinv[rid];
            }
    }
}

// ---------------------------------------------------------------------------
extern "C" void kernel_launch(void* const* d_in, const int* in_sizes, int n_in,
                              void* d_out, int out_size, void* d_ws, size_t ws_size,
                              hipStream_t stream) {
    (void)in_sizes; (void)n_in; (void)out_size; (void)ws_size;
    const float* x  = (const float*)d_in[0];
    const float* Wq = (const float*)d_in[1];
    const float* Wk = (const float*)d_in[2];
    const float* Wv = (const float*)d_in[3];
    float* outp = (float*)d_out;

    char* ws = (char*)d_ws;                       // 5.75 MB used (< 6 MB proven)
    short* wt = (short*)ws;                       // [3][2][64][1024]  768 KB
    short* qh = (short*)(ws + 786432);            // [8192][64] bf16 hi (x8)
    short* ql = (short*)(ws + 786432 + 1048576);
    short* kh = (short*)(ws + 786432 + 2 * 1048576);
    short* kl = (short*)(ws + 786432 + 3 * 1048576);
    short* vt = (short*)(ws + 786432 + 4 * 1048576);  // [4][64][2048] bf16

    prep_w_kernel<<<dim3(16, 3), 256, 0, stream>>>(Wq, Wk, Wv, wt);
    qkv_proj_kernel<<<dim3(128, 3), 256, 0, stream>>>(x, wt, qh, ql, kh, kl, vt);
    attn_kernel<<<dim3(256), 512, 0, stream>>>(qh, ql, kh, kl, vt, outp);
}

// Round 3
// 155.835 us; speedup vs baseline: 2.3717x; 1.0097x over previous
//
#include <hip/hip_runtime.h>
#include <math.h>

#define T_  2048
#define C_  1024
#define HD_ 64

typedef __attribute__((ext_vector_type(8))) short bf16x8;   // 8 bf16 = 4 VGPRs
typedef __attribute__((ext_vector_type(4))) float f32x4;    // MFMA C/D

#define MFMA_BF16(A, B, C) __builtin_amdgcn_mfma_f32_16x16x32_bf16(A, B, C, 0, 0, 0)

__device__ __forceinline__ short f2bf(float f) {
    union { float f; unsigned u; } v; v.f = f;
    unsigned r = v.u + 0x7fffu + ((v.u >> 16) & 1u);   // RTNE
    return (short)(r >> 16);
}
__device__ __forceinline__ float bf2f(short s) {
    union { float f; unsigned u; } v;
    v.u = ((unsigned)(unsigned short)s) << 16;
    return v.f;
}

// ---------------------------------------------------------------------------
// K0: W[1024][64] fp32  ->  Wt[m][hi/lo][64 h][1024 c] bf16 (transposed+split)
// ---------------------------------------------------------------------------
__global__ __launch_bounds__(256) void prep_w_kernel(
    const float* __restrict__ Wq, const float* __restrict__ Wk,
    const float* __restrict__ Wv, short* __restrict__ wt)
{
    const int m = blockIdx.y;
    const float* W = (m == 0) ? Wq : (m == 1) ? Wk : Wv;
    const int t = threadIdx.x;
    const int c = blockIdx.x * 64 + (t >> 2);
    const int hg = (t & 3) * 16;
    const float4* wp = (const float4*)(W + (size_t)c * HD_ + hg);
    short* hi = wt + (size_t)(m * 2 + 0) * 64 * 1024;
    short* lo = wt + (size_t)(m * 2 + 1) * 64 * 1024;
    #pragma unroll
    for (int u = 0; u < 4; ++u) {
        float4 f = wp[u];
        float vs[4] = {f.x, f.y, f.z, f.w};
        #pragma unroll
        for (int e = 0; e < 4; ++e) {
            int h = hg + u * 4 + e;
            short hh = f2bf(vs[e]);
            hi[(size_t)h * 1024 + c] = hh;
            lo[(size_t)h * 1024 + c] = f2bf(vs[e] - bf2f(hh));
        }
    }
}

// ---------------------------------------------------------------------------
// K1: merged QKV projection. Block = 32 rows of x, ALL of q,k,v. 256 thr.
// Wave w owns col-tiles {q: w*16.., k: w*16.., v: w*16..} (ct = w + cl*4).
// q,k: triple-product hi/lo, normal operands. v: single-plane, swapped
// operands -> transposed D[h][t] for coalesced vT writes.
// x converted to hi/lo bf16 ONCE per block (was 3x in R2).
// ---------------------------------------------------------------------------
__global__ __launch_bounds__(256) void qkv_proj_kernel(
    const float* __restrict__ x, const short* __restrict__ wt,
    short* __restrict__ qhp, short* __restrict__ qlp,
    short* __restrict__ khp, short* __restrict__ klp,
    short* __restrict__ vtp)
{
    __shared__ __align__(16) short xh[32 * 64], xl[32 * 64];   // 4 KB each
    __shared__ __align__(16) short wh[192 * 64], wl[192 * 64]; // 24 KB each

    const int t = threadIdx.x, L = t & 63, wv = t >> 6;
    const int R0 = blockIdx.x * 32;
    const int xrow = t >> 3, xch = t & 7;

    f32x4 acc[2][3];
    #pragma unroll
    for (int i = 0; i < 2; ++i)
        #pragma unroll
        for (int j = 0; j < 3; ++j) acc[i][j] = {0.f, 0.f, 0.f, 0.f};

    // prefetch registers
    float4 xa0, xa1;
    bf16x8 wr[2][6];
    const float* xp = x + (size_t)(R0 + xrow) * C_ + xch * 8;

    auto loadX = [&](int c0) {
        xa0 = *(const float4*)(xp + c0);
        xa1 = *(const float4*)(xp + c0 + 4);
    };
    auto loadW = [&](int c0) {
        #pragma unroll
        for (int pl = 0; pl < 2; ++pl)
            #pragma unroll
            for (int u = 0; u < 6; ++u) {
                int cc = t + 256 * u;          // 0..1535
                int row = cc >> 3, ch = cc & 7;
                int m = row >> 6, h = row & 63;
                wr[pl][u] = *(const bf16x8*)(wt + (size_t)(m * 2 + pl) * 65536
                                             + (size_t)h * 1024 + c0 + ch * 8);
            }
    };

    loadX(0); loadW(0);
    for (int c0 = 0; c0 < C_; c0 += 64) {
        __syncthreads();
        {   // store x hi/lo
            float vs[8] = {xa0.x, xa0.y, xa0.z, xa0.w, xa1.x, xa1.y, xa1.z, xa1.w};
            bf16x8 vh, vl;
            #pragma unroll
            for (int e = 0; e < 8; ++e) {
                short hh = f2bf(vs[e]);
                vh[e] = hh;
                vl[e] = f2bf(vs[e] - bf2f(hh));
            }
            int slot = (xch ^ (xrow & 7)) * 8;
            *(bf16x8*)&xh[xrow * 64 + slot] = vh;
            *(bf16x8*)&xl[xrow * 64 + slot] = vl;
        }
        {   // store W
            #pragma unroll
            for (int pl = 0; pl < 2; ++pl)
                #pragma unroll
                for (int u = 0; u < 6; ++u) {
                    int cc = t + 256 * u;
                    int row = cc >> 3, ch = cc & 7;
                    short* dst = pl ? wl : wh;
                    *(bf16x8*)&dst[row * 64 + ((ch ^ (row & 7)) * 8)] = wr[pl][u];
                }
        }
        if (c0 + 64 < C_) { loadX(c0 + 64); loadW(c0 + 64); }
        __syncthreads();
        #pragma unroll
        for (int kc = 0; kc < 2; ++kc) {
            const int ch = kc * 4 + (L >> 4);
            bf16x8 axh[2], axl[2], bwh[3], bwl[3];
            #pragma unroll
            for (int rt = 0; rt < 2; ++rt) {
                int row = rt * 16 + (L & 15);
                int off = row * 64 + ((ch ^ (row & 7)) * 8);
                axh[rt] = *(const bf16x8*)&xh[off];
                axl[rt] = *(const bf16x8*)&xl[off];
            }
            #pragma unroll
            for (int cl = 0; cl < 3; ++cl) {
                int ct = wv + cl * 4;          // cl0: q, cl1: k, cl2: v
                int wrow = ct * 16 + (L & 15);
                int off = wrow * 64 + ((ch ^ (wrow & 7)) * 8);
                bwh[cl] = *(const bf16x8*)&wh[off];
                bwl[cl] = *(const bf16x8*)&wl[off];
            }
            #pragma unroll
            for (int rt = 0; rt < 2; ++rt) {
                // q (triple)
                acc[rt][0] = MFMA_BF16(axl[rt], bwh[0], acc[rt][0]);
                acc[rt][0] = MFMA_BF16(axh[rt], bwl[0], acc[rt][0]);
                acc[rt][0] = MFMA_BF16(axh[rt], bwh[0], acc[rt][0]);
                // k (triple)
                acc[rt][1] = MFMA_BF16(axl[rt], bwh[1], acc[rt][1]);
                acc[rt][1] = MFMA_BF16(axh[rt], bwl[1], acc[rt][1]);
                acc[rt][1] = MFMA_BF16(axh[rt], bwh[1], acc[rt][1]);
                // v (single plane, swapped -> D[h][t])
                acc[rt][2] = MFMA_BF16(bwh[2], axh[rt], acc[rt][2]);
            }
        }
    }

    // ---- epilogue
    const int quad = L >> 4;
    #pragma unroll
    for (int rt = 0; rt < 2; ++rt) {
        #pragma unroll
        for (int r = 0; r < 4; ++r) {
            int row = R0 + rt * 16 + quad * 4 + r;
            int h = wv * 16 + (L & 15);
            // q
            float vq = acc[rt][0][r] * 8.f;
            short hq = f2bf(vq);
            qhp[(size_t)row * HD_ + h] = hq;
            qlp[(size_t)row * HD_ + h] = f2bf(vq - bf2f(hq));
            // k
            float vk = acc[rt][1][r];
            short hk = f2bf(vk);
            khp[(size_t)row * HD_ + h] = hk;
            klp[(size_t)row * HD_ + h] = f2bf(vk - bf2f(hk));
            // v (transposed): d = wv*16+quad*4+r, t-col = R0+rt*16+(L&15)
            int d = wv * 16 + quad * 4 + r;
            int tt = R0 + rt * 16 + (L & 15);
            int bb = tt >> 11, tl = tt & (T_ - 1);
            vtp[(size_t)(bb * 64 + d) * T_ + tl] = f2bf(acc[rt][2][r]);
        }
    }
}

// ---------------------------------------------------------------------------
// K2a: full-row softmax stats (first softmax is UNMASKED). Block = (b,
// 64-row tile, 512-col segment): 512 blocks = 2/CU. Q resident in registers.
// Writes per-segment partial (m,l) to pm.
// ---------------------------------------------------------------------------
__global__ __launch_bounds__(256) void stats_kernel(
    const short* __restrict__ qhp, const short* __restrict__ qlp,
    const short* __restrict__ khp, const short* __restrict__ klp,
    float* __restrict__ pm)
{
    __shared__ __align__(16) short khs[64 * 64], kls[64 * 64];  // 8 KB each
    __shared__ float red[4 * 64 * 2];

    const int t = threadIdx.x, L = t & 63, wv = t >> 6;
    const int bt = blockIdx.x, seg = blockIdx.y, b = blockIdx.z;
    const int R0 = bt * 64, S0 = seg * 512;

    // Q fragments resident: 4 row-tiles x 2 d-chunks x 2 planes
    bf16x8 qfh[4][2], qfl[4][2];
    #pragma unroll
    for (int rt = 0; rt < 4; ++rt)
        #pragma unroll
        for (int dc = 0; dc < 2; ++dc) {
            int row = R0 + rt * 16 + (L & 15);
            size_t off = ((size_t)b * T_ + row) * HD_ + dc * 32 + (L >> 4) * 8;
            qfh[rt][dc] = *(const bf16x8*)(qhp + off);
            qfl[rt][dc] = *(const bf16x8*)(qlp + off);
        }

    float ml[4][4], ll[4][4];
    #pragma unroll
    for (int rt = 0; rt < 4; ++rt)
        #pragma unroll
        for (int r = 0; r < 4; ++r) { ml[rt][r] = -1e30f; ll[rt][r] = 0.f; }

    const int pl = t >> 7, id = t & 127;
    for (int jt = 0; jt < 8; ++jt) {
        __syncthreads();
        {
            const short* src = pl ? klp : khp;
            short* dst = pl ? kls : khs;
            #pragma unroll
            for (int u = 0; u < 4; ++u) {
                int cid = id * 4 + u;              // 0..511
                int col = cid >> 3, ch = cid & 7;
                bf16x8 v = *(const bf16x8*)(src
                    + ((size_t)b * T_ + S0 + jt * 64 + col) * HD_ + ch * 8);
                *(bf16x8*)&dst[col * 64 + ((ch ^ (col & 7)) * 8)] = v;
            }
        }
        __syncthreads();
        const int colL = wv * 16 + (L & 15);
        bf16x8 kf[2], kfl[2];
        #pragma unroll
        for (int dc = 0; dc < 2; ++dc) {
            int ch = dc * 4 + (L >> 4);
            int off = colL * 64 + ((ch ^ (colL & 7)) * 8);
            kf[dc]  = *(const bf16x8*)&khs[off];
            kfl[dc] = *(const bf16x8*)&kls[off];
        }
        #pragma unroll
        for (int rt = 0; rt < 4; ++rt) {
            f32x4 s = {0.f, 0.f, 0.f, 0.f};
            #pragma unroll
            for (int dc = 0; dc < 2; ++dc) {
                s = MFMA_BF16(qfl[rt][dc], kf[dc], s);
                s = MFMA_BF16(qfh[rt][dc], kfl[dc], s);
                s = MFMA_BF16(qfh[rt][dc], kf[dc], s);
            }
            #pragma unroll
            for (int r = 0; r < 4; ++r) {
                float mn = fmaxf(ml[rt][r], s[r]);
                ll[rt][r] = ll[rt][r] * __expf(ml[rt][r] - mn) + __expf(s[r] - mn);
                ml[rt][r] = mn;
            }
        }
    }
    // merge the 16 columns within each wave
    #pragma unroll
    for (int off = 1; off < 16; off <<= 1)
        #pragma unroll
        for (int rt = 0; rt < 4; ++rt)
            #pragma unroll
            for (int r = 0; r < 4; ++r) {
                float mo = __shfl_xor(ml[rt][r], off, 64);
                float lo = __shfl_xor(ll[rt][r], off, 64);
                float mn = fmaxf(ml[rt][r], mo);
                ll[rt][r] = ll[rt][r] * __expf(ml[rt][r] - mn) + lo * __expf(mo - mn);
                ml[rt][r] = mn;
            }
    if ((L & 15) == 0) {
        #pragma unroll
        for (int rt = 0; rt < 4; ++rt)
            #pragma unroll
            for (int r = 0; r < 4; ++r) {
                int row = rt * 16 + (L >> 4) * 4 + r;
                red[(wv * 64 + row) * 2 + 0] = ml[rt][r];
                red[(wv * 64 + row) * 2 + 1] = ll[rt][r];
            }
    }
    __syncthreads();
    if (t < 64) {
        float M = red[t * 2], S = red[t * 2 + 1];
        #pragma unroll
        for (int w = 1; w < 4; ++w) {
            float mo = red[(w * 64 + t) * 2], lo = red[(w * 64 + t) * 2 + 1];
            float mn = fmaxf(M, mo);
            S = S * __expf(M - mn) + lo * __expf(mo - mn);
            M = mn;
        }
        size_t o = ((size_t)((b * 32 + bt) * 4 + seg) * 64 + t) * 2;
        pm[o] = M;
        pm[o + 1] = S;
    }
}

// ---------------------------------------------------------------------------
// K2b: merge the 4 segment partials -> m, 1/l per row.
// ---------------------------------------------------------------------------
__global__ __launch_bounds__(256) void stat_merge_kernel(
    const float* __restrict__ pm, float* __restrict__ msp, float* __restrict__ ilp)
{
    int gid = blockIdx.x * 256 + threadIdx.x;     // 0..8191
    int b = gid >> 11, rl = gid & 2047, bt = rl >> 6, rr = rl & 63;
    float M = -1e30f, S = 0.f;
    #pragma unroll
    for (int seg = 0; seg < 4; ++seg) {
        size_t o = ((size_t)((b * 32 + bt) * 4 + seg) * 64 + rr) * 2;
        float mo = pm[o], lo = pm[o + 1];
        float mn = fmaxf(M, mo);
        S = S * __expf(M - mn) + lo * __expf(mo - mn);
        M = mn;
    }
    msp[gid] = M;
    ilp[gid] = 1.f / S;
}

// ---------------------------------------------------------------------------
// K2c: causal second softmax + PV. Block = (b, paired tiles p & 127-p),
// 512 thr = 8 waves. Stats precomputed. es is fp32, chunk-XOR swizzled.
// ---------------------------------------------------------------------------
__global__ __launch_bounds__(512) void pv_kernel(
    const short* __restrict__ qhp, const short* __restrict__ qlp,
    const short* __restrict__ khp, const short* __restrict__ klp,
    const short* __restrict__ vtp, const float* __restrict__ msp,
    const float* __restrict__ ilp, float* __restrict__ out)
{
    __shared__ __align__(16) short khs[128 * 64];   // 16 KB
    __shared__ __align__(16) short kls[128 * 64];   // 16 KB
    __shared__ __align__(16) short vts[64 * 128];   // 16 KB
    __shared__ __align__(16) float es[32 * 128];    // 16 KB (total 64 KB)

    const int t = threadIdx.x, L = t & 63, wv = t >> 6;
    const int b = blockIdx.x >> 6, p = blockIdx.x & 63;
    const int IA = p * 16, IB = (127 - p) * 16;

    // q fragments
    bf16x8 qfh[2][2], qfl[2][2];
    #pragma unroll
    for (int rt = 0; rt < 2; ++rt) {
        int row = (rt ? IB : IA) + (L & 15);
        const short* qb  = qhp + ((size_t)b * T_ + row) * HD_;
        const short* qbl = qlp + ((size_t)b * T_ + row) * HD_;
        #pragma unroll
        for (int dc = 0; dc < 2; ++dc) {
            int off = dc * 32 + (L >> 4) * 8;
            qfh[rt][dc] = *(const bf16x8*)(qb + off);
            qfl[rt][dc] = *(const bf16x8*)(qbl + off);
        }
    }
    // stats
    float ms[2][4], is[2][4];
    int rowg[2][4];
    #pragma unroll
    for (int rt = 0; rt < 2; ++rt)
        #pragma unroll
        for (int r = 0; r < 4; ++r) {
            int rg = (rt ? IB : IA) + (L >> 4) * 4 + r;
            rowg[rt][r] = rg;
            ms[rt][r] = msp[b * T_ + rg];
            is[rt][r] = ilp[b * T_ + rg];
        }

    const short* kbh = khp + (size_t)b * T_ * HD_;
    const short* kbl = klp + (size_t)b * T_ * HD_;
    const short* vb  = vtp + (size_t)b * 64 * T_;
    const int spl = t >> 8, sid = t & 255;

    auto stageK = [&](int jt) {
        const short* src = spl ? kbl : kbh;
        short* dst = spl ? kls : khs;
        #pragma unroll
        for (int u = 0; u < 4; ++u) {
            int cid = sid * 4 + u;                 // 0..1023
            int col = cid >> 3, c8 = cid & 7;
            bf16x8 v = *(const bf16x8*)(src + (size_t)(jt * 128 + col) * HD_ + c8 * 8);
            *(bf16x8*)&dst[col * 64 + ((c8 ^ (col & 7)) * 8)] = v;
        }
    };
    auto stageV = [&](int jt) {
        #pragma unroll
        for (int u = 0; u < 2; ++u) {
            int cid = t + u * 512;                 // 0..1023
            int d = cid >> 4, ch = cid & 15;
            bf16x8 v = *(const bf16x8*)(vb + (size_t)d * T_ + jt * 128 + ch * 8);
            *(bf16x8*)&vts[d * 128 + ((ch ^ ((d & 7) * 2)) * 8)] = v;
        }
    };

    const int nA = (IA + 143) >> 7;
    const int nB = (IB + 143) >> 7;
    const int rtp = wv & 1, dh = (wv >> 1) & 1, khf = wv >> 2;
    f32x4 ov[2];
    ov[0] = {0.f, 0.f, 0.f, 0.f};
    ov[1] = {0.f, 0.f, 0.f, 0.f};
    float dn[2][4];
    #pragma unroll
    for (int rt = 0; rt < 2; ++rt)
        #pragma unroll
        for (int r = 0; r < 4; ++r) dn[rt][r] = 0.f;

    for (int jt = 0; jt < nB; ++jt) {
        __syncthreads();
        stageK(jt);
        stageV(jt);
        __syncthreads();
        const int col = wv * 16 + (L & 15);
        bf16x8 kf[2], kfl[2];
        #pragma unroll
        for (int dc = 0; dc < 2; ++dc) {
            int ch = dc * 4 + (L >> 4);
            int off = col * 64 + ((ch ^ (col & 7)) * 8);
            kf[dc]  = *(const bf16x8*)&khs[off];
            kfl[dc] = *(const bf16x8*)&kls[off];
        }
        for (int rt = 0; rt < 2; ++rt) {
            if (rt == 0 && jt >= nA) continue;     // block-uniform
            f32x4 s = {0.f, 0.f, 0.f, 0.f};
            #pragma unroll
            for (int dc = 0; dc < 2; ++dc) {
                s = MFMA_BF16(qfl[rt][dc], kf[dc], s);
                s = MFMA_BF16(qfh[rt][dc], kfl[dc], s);
                s = MFMA_BF16(qfh[rt][dc], kf[dc], s);
            }
            #pragma unroll
            for (int r = 0; r < 4; ++r) {
                float pv = __expf(s[r] - ms[rt][r]) * is[rt][r];
                int colg = jt * 128 + col;
                float ev = (colg <= rowg[rt][r]) ? __expf(pv) : 0.f;
                dn[rt][r] += ev;
                int rid = rt * 16 + (L >> 4) * 4 + r;
                es[rid * 128 + (((col >> 3) ^ (rid & 15)) * 8) + (col & 7)] = ev;
            }
        }
        __syncthreads();
        if (!(rtp == 0 && jt >= nA)) {
            #pragma unroll
            for (int u = 0; u < 2; ++u) {
                int kc = khf * 2 + u;
                int rid = rtp * 16 + (L & 15);
                int chunk = (kc * 4 + (L >> 4)) ^ (rid & 15);
                const float* ep = &es[rid * 128 + chunk * 8];
                float4 e0 = *(const float4*)ep;
                float4 e1 = *(const float4*)(ep + 4);
                bf16x8 ef;
                ef[0] = f2bf(e0.x); ef[1] = f2bf(e0.y);
                ef[2] = f2bf(e0.z); ef[3] = f2bf(e0.w);
                ef[4] = f2bf(e1.x); ef[5] = f2bf(e1.y);
                ef[6] = f2bf(e1.z); ef[7] = f2bf(e1.w);
                #pragma unroll
                for (int dt = 0; dt < 2; ++dt) {
                    int d = dh * 32 + dt * 16 + (L & 15);
                    int ch = kc * 4 + (L >> 4);
                    bf16x8 vf = *(const bf16x8*)&vts[d * 128 + ((ch ^ ((d & 7) * 2)) * 8)];
                    ov[dt] = MFMA_BF16(ef, vf, ov[dt]);
                }
            }
        }
    }

    // ---- den reduce (reuse tail of es; obuf reuses head)
    #pragma unroll
    for (int off = 1; off < 16; off <<= 1)
        #pragma unroll
        for (int rt = 0; rt < 2; ++rt)
            #pragma unroll
            for (int r = 0; r < 4; ++r)
                dn[rt][r] += __shfl_xor(dn[rt][r], off, 64);
    __syncthreads();                // all PV reads of es done
    float* red  = es + 2304;        // 256 floats
    float* dinv = es + 2560;        // 32 floats
    if ((L & 15) == 0) {
        #pragma unroll
        for (int rt = 0; rt < 2; ++rt)
            #pragma unroll
            for (int r = 0; r < 4; ++r) {
                int rid = rt * 16 + (L >> 4) * 4 + r;
                red[wv * 32 + rid] = dn[rt][r];
            }
    }
    __syncthreads();
    if (t < 32) {
        float D = 0.f;
        #pragma unroll
        for (int w = 0; w < 8; ++w) D += red[w * 32 + t];
        dinv[t] = 1.f / D;
    }
    float* obuf = es;               // 2048 floats
    __syncthreads();
    if (khf == 1) {
        #pragma unroll
        for (int dt = 0; dt < 2; ++dt)
            #pragma unroll
            for (int r = 0; r < 4; ++r)
                obuf[((wv - 4) * 64 + L) * 8 + dt * 4 + r] = ov[dt][r];
    }
    __syncthreads();
    if (khf == 0) {
        float* ob = out + (size_t)b * T_ * HD_;
        #pragma unroll
        for (int dt = 0; dt < 2; ++dt)
            #pragma unroll
            for (int r = 0; r < 4; ++r) {
                float o = ov[dt][r] + obuf[(wv * 64 + L) * 8 + dt * 4 + r];
                int rid = rtp * 16 + (L >> 4) * 4 + r;
                int row = (rtp ? IB : IA) + (L >> 4) * 4 + r;
                int d = dh * 32 + dt * 16 + (L & 15);
                ob[(size_t)row * HD_ + d] = o * dinv[rid];
            }
    }
}

// ---------------------------------------------------------------------------
extern "C" void kernel_launch(void* const* d_in, const int* in_sizes, int n_in,
                              void* d_out, int out_size, void* d_ws, size_t ws_size,
                              hipStream_t stream) {
    (void)in_sizes; (void)n_in; (void)out_size; (void)ws_size;
    const float* x  = (const float*)d_in[0];
    const float* Wq = (const float*)d_in[1];
    const float* Wk = (const float*)d_in[2];
    const float* Wv = (const float*)d_in[3];
    float* outp = (float*)d_out;

    char* ws = (char*)d_ws;                       // 5.75 MB used (proven size)
    short* wt  = (short*)ws;                      // 768 KB (dead after proj)
    float* pm  = (float*)ws;                      // 256 KB (stats partials, reuses wt)
    float* msp = (float*)(ws + 262144);           // 32 KB
    float* ilp = (float*)(ws + 294912);           // 32 KB
    short* qh = (short*)(ws + 786432);
    short* ql = (short*)(ws + 786432 + 1048576);
    short* kh = (short*)(ws + 786432 + 2 * 1048576);
    short* kl = (short*)(ws + 786432 + 3 * 1048576);
    short* vt = (short*)(ws + 786432 + 4 * 1048576);  // [4][64][2048] bf16

    prep_w_kernel<<<dim3(16, 3), 256, 0, stream>>>(Wq, Wk, Wv, wt);
    qkv_proj_kernel<<<dim3(256), 256, 0, stream>>>(x, wt, qh, ql, kh, kl, vt);
    stats_kernel<<<dim3(32, 4, 4), 256, 0, stream>>>(qh, ql, kh, kl, pm);
    stat_merge_kernel<<<dim3(32), 256, 0, stream>>>(pm, msp, ilp);
    pv_kernel<<<dim3(256), 512, 0, stream>>>(qh, ql, kh, kl, vt, msp, ilp, outp);
}